// Round 11
// baseline (97.454 us; speedup 1.0000x reference)
//
#include <hip/hip_runtime.h>

// MLP: 30->24->19->14->10->6->2->1, ReLU between all but last layer.
// One row per thread. Two fixes vs round-1 baseline:
//  (1) x is staged into LDS with fully-COALESCED float4 global loads
//      (round-1/6 read x with 120-B-strided per-lane loads -> ~64 cache
//      lines per wave-instr -> TA serialization was the shared 66us floor).
//      LDS x rows use stride 34 floats (136 B): 8B-aligned ds_read_b64,
//      bank=(2t+2i)%32 -> uniform 2-way conflict = free.
//  (2) weights stay in LDS (beat the SGPR-weight variant 62% vs 50% VALU),
//      rows padded to 4-float multiples -> 16B-aligned ds_read_b128 broadcast.

#define NTHREADS 256
#define XSTRIDE  34            // floats per LDS x row
#define WFLOATS  1832          // padded weights + biases
#define XBASE    WFLOATS       // x slab starts after weights (byte 7328, 16B-aligned)

// Padded weight layout (floats):
//  W1@0:24x32  W2@768:19x24  W3@1224:14x20  W4@1504:10x16
//  W5@1664:6x12  W6@1736:2x8  W7@1752:1x4   biases @1756..1831

template <int FIN, int PAD, int FOUT>
__device__ __forceinline__ void stage_w(const float* __restrict__ g, float* __restrict__ s, int t) {
    for (int idx = t; idx < FOUT * PAD; idx += NTHREADS) {
        int r = idx / PAD;
        int c = idx - r * PAD;
        s[idx] = (c < FIN) ? g[r * FIN + c] : 0.0f;
    }
}

template <int FIN, int PAD, int FOUT, bool RELU>
__device__ __forceinline__ void layer(const float* __restrict__ wl, const float* __restrict__ bl,
                                      const float* __restrict__ in, float* __restrict__ outv) {
#pragma unroll
    for (int j = 0; j < FOUT; ++j) {
        float acc = bl[j];
        const float4* wr = (const float4*)(wl + j * PAD);
#pragma unroll
        for (int k4 = 0; k4 < PAD / 4; ++k4) {
            float4 w4 = wr[k4];
            if (4 * k4 + 0 < FIN) acc = fmaf(w4.x, in[4 * k4 + 0], acc);
            if (4 * k4 + 1 < FIN) acc = fmaf(w4.y, in[4 * k4 + 1], acc);
            if (4 * k4 + 2 < FIN) acc = fmaf(w4.z, in[4 * k4 + 2], acc);
            if (4 * k4 + 3 < FIN) acc = fmaf(w4.w, in[4 * k4 + 3], acc);
        }
        outv[j] = RELU ? fmaxf(acc, 0.0f) : acc;
    }
}

__global__ __launch_bounds__(NTHREADS) void mlp_stagex(
    const float* __restrict__ x,
    const float* __restrict__ W1, const float* __restrict__ B1,
    const float* __restrict__ W2, const float* __restrict__ B2,
    const float* __restrict__ W3, const float* __restrict__ B3,
    const float* __restrict__ W4, const float* __restrict__ B4,
    const float* __restrict__ W5, const float* __restrict__ B5,
    const float* __restrict__ W6, const float* __restrict__ B6,
    const float* __restrict__ W7, const float* __restrict__ B7,
    float* __restrict__ out, int nrows)
{
    __shared__ float s[WFLOATS + NTHREADS * XSTRIDE];   // 42,144 B
    const int t = threadIdx.x;

    stage_w<30, 32, 24>(W1, s + 0,    t);
    stage_w<24, 24, 19>(W2, s + 768,  t);
    stage_w<19, 20, 14>(W3, s + 1224, t);
    stage_w<14, 16, 10>(W4, s + 1504, t);
    stage_w<10, 12, 6 >(W5, s + 1664, t);
    stage_w<6,  8,  2 >(W6, s + 1736, t);
    stage_w<2,  4,  1 >(W7, s + 1752, t);
    if (t < 24) s[1756 + t] = B1[t];
    if (t < 19) s[1780 + t] = B2[t];
    if (t < 14) s[1799 + t] = B3[t];
    if (t < 10) s[1813 + t] = B4[t];
    if (t < 6)  s[1823 + t] = B5[t];
    if (t < 2)  s[1829 + t] = B6[t];
    if (t < 1)  s[1831 + t] = B7[t];

    // ---- coalesced x staging: 256 rows x 30 floats = 1920 float4 ----
    {
        const size_t total  = (size_t)nrows * 30;
        const size_t slab0  = (size_t)blockIdx.x * (NTHREADS * 30);
        const float4* xs    = (const float4*)(x + slab0);
        const size_t  rem4  = (total > slab0) ? ((total - slab0) >> 2) : 0;
        const int     nf4   = (int)((rem4 < (size_t)(NTHREADS * 30 / 4)) ? rem4 : (size_t)(NTHREADS * 30 / 4));
        for (int i = t; i < nf4; i += NTHREADS) {
            float4 v = xs[i];                 // consecutive lanes -> consecutive 16B
            int fi = 4 * i;
            int r  = fi / 30;                 // magic-mul
            int c  = fi - 30 * r;             // c is even, <= 28
            float* rowp = s + XBASE + r * XSTRIDE;
            *(float2*)(rowp + c) = make_float2(v.x, v.y);
            if (c == 28)
                *(float2*)(s + XBASE + (r + 1) * XSTRIDE) = make_float2(v.z, v.w);
            else
                *(float2*)(rowp + c + 2) = make_float2(v.z, v.w);
        }
    }
    __syncthreads();

    const int row = blockIdx.x * NTHREADS + t;
    if (row >= nrows) return;

    // row read from LDS: 15x ds_read_b64, 2-way bank alias (free)
    float xr[30];
    const float2* rp = (const float2*)(s + XBASE + t * XSTRIDE);
#pragma unroll
    for (int i = 0; i < 15; ++i) {
        float2 v = rp[i];
        xr[2 * i + 0] = v.x;
        xr[2 * i + 1] = v.y;
    }

    float h1[24]; layer<30, 32, 24, true >(s + 0,    s + 1756, xr, h1);
    float h2[19]; layer<24, 24, 19, true >(s + 768,  s + 1780, h1, h2);
    float h3[14]; layer<19, 20, 14, true >(s + 1224, s + 1799, h2, h3);
    float h4[10]; layer<14, 16, 10, true >(s + 1504, s + 1813, h3, h4);
    float h5[6];  layer<10, 12, 6,  true >(s + 1664, s + 1823, h4, h5);
    float h6[2];  layer<6,  8,  2,  true >(s + 1736, s + 1829, h5, h6);
    float h7[1];  layer<2,  4,  1,  false>(s + 1752, s + 1831, h6, h7);

    out[row] = h7[0];
}

extern "C" void kernel_launch(void* const* d_in, const int* in_sizes, int n_in,
                              void* d_out, int out_size, void* d_ws, size_t ws_size,
                              hipStream_t stream) {
    const float* x = (const float*)d_in[0];
    int nrows = in_sizes[0] / 30;
    int blocks = (nrows + NTHREADS - 1) / NTHREADS;
    mlp_stagex<<<blocks, NTHREADS, 0, stream>>>(
        x,
        (const float*)d_in[1],  (const float*)d_in[2],
        (const float*)d_in[3],  (const float*)d_in[4],
        (const float*)d_in[5],  (const float*)d_in[6],
        (const float*)d_in[7],  (const float*)d_in[8],
        (const float*)d_in[9],  (const float*)d_in[10],
        (const float*)d_in[11], (const float*)d_in[12],
        (const float*)d_in[13], (const float*)d_in[14],
        (float*)d_out, nrows);
}